// Round 6
// baseline (688.383 us; speedup 1.0000x reference)
//
#include <hip/hip_runtime.h>
#include <math.h>

#define DD   120
#define KPAD 128
#define KP   136          // LDS row stride in bf16 elems (272 B: 2-way bank alias = free)
#define MT   64           // points per block
#define NTHR 512          // 8 waves; wave h owns head h (cols 15h..15h+14)
#define HASH_MASK 1048575LL
#define MODT 201

typedef short  short8  __attribute__((ext_vector_type(8)));
typedef float  floatx4 __attribute__((ext_vector_type(4)));

__device__ __forceinline__ unsigned short f2b(float f) {
    __bf16 h = (__bf16)f;                       // RNE hardware cvt
    return __builtin_bit_cast(unsigned short, h);
}
__device__ __forceinline__ float b2f(unsigned short u) {
    unsigned int x = ((unsigned int)u) << 16;   // exact widening
    return __builtin_bit_cast(float, x);
}
// 16-lane sum via DPP row_ror (pure VALU — no DS-pipe latency chain)
template<int CTRL>
__device__ __forceinline__ float dpp_add(float v) {
    int y = __builtin_amdgcn_update_dpp(0, __builtin_bit_cast(int, v),
                                        CTRL, 0xF, 0xF, false);
    return v + __builtin_bit_cast(float, y);
}
__device__ __forceinline__ float rsum16(float v) {
    v = dpp_add<0x128>(v);   // row_ror:8
    v = dpp_add<0x124>(v);   // row_ror:4
    v = dpp_add<0x122>(v);   // row_ror:2
    v = dpp_add<0x121>(v);   // row_ror:1
    return v;
}
__device__ __forceinline__ uint2 pack4(float4 v) {
    unsigned int lo = (unsigned int)f2b(v.x) | ((unsigned int)f2b(v.y) << 16);
    unsigned int hi = (unsigned int)f2b(v.z) | ((unsigned int)f2b(v.w) << 16);
    return make_uint2(lo, hi);
}

// ---------------------------------------------------------------------------
// Pre-pass 1: weights fp32 [K=120][N=120] -> bf16 W^T padded [N=128][K=128].
// ---------------------------------------------------------------------------
__global__ __launch_bounds__(256)
void prep_weights(const float* __restrict__ td_w, const float* __restrict__ sd_w,
                  unsigned short* __restrict__ wt)
{
    int idx = blockIdx.x * 256 + threadIdx.x;   // 8*128*128 = 131072 total
    int mat = idx >> 14;
    int k   = (idx >> 7) & 127;
    int n   = idx & 127;
    const float* src = (mat < 4) ? (td_w + mat * DD * DD) : (sd_w + (mat - 4) * DD * DD);
    float v = (n < DD && k < DD) ? src[k * DD + n] : 0.f;
    wt[(mat << 14) + (n << 7) + k] = f2b(v);
}

// ---------------------------------------------------------------------------
// Pre-pass 1b: fused weights W31 = W3@U1, W32 = W3@U2 (bf16 W^T padded) and
// fused biases fb[0][n] = b3@U1 + b_k2, fb[1][n] = b3@U2 + b_v2.
// cond = o1@W3+b3 is only ever consumed via @U1 / @U2  =>  eliminate it.
// ---------------------------------------------------------------------------
__global__ __launch_bounds__(256)
void prep_fused(const float* __restrict__ td_w, const float* __restrict__ td_b,
                const float* __restrict__ sd_w, const float* __restrict__ sd_b,
                unsigned short* __restrict__ wf, float* __restrict__ fb)
{
    int idx = blockIdx.x * 256 + threadIdx.x;   // 2*128*128 = 32768 total
    int mat = idx >> 14;                        // 0 => W3@U1, 1 => W3@U2
    int k   = (idx >> 7) & 127;
    int n   = idx & 127;
    const float* W3 = td_w + 3 * DD * DD;
    const float* Um = sd_w + (mat + 1) * DD * DD;
    float acc = 0.f;
    if (n < DD && k < DD) {
        for (int j = 0; j < DD; j++)
            acc = fmaf(W3[k * DD + j], Um[j * DD + n], acc);
    }
    wf[(mat << 14) + (n << 7) + k] = f2b(acc);
    if (k == DD) {                 // one thread per (mat,n): fused bias (0 for pads)
        float s = 0.f;
        if (n < DD) {
            s = sd_b[(mat + 1) * DD + n];
            for (int j = 0; j < DD; j++)
                s = fmaf(td_b[3 * DD + j], Um[j * DD + n], s);
        }
        fb[(mat << 7) + n] = s;
    }
}

// ---------------------------------------------------------------------------
// Pre-pass 2: k1t[t] = te[t]@W1+b1, v1t[t] = te[t]@W2+b2 for 201 time rows.
// ---------------------------------------------------------------------------
__global__ __launch_bounds__(128)
void prep_te(const float* __restrict__ temb, const float* __restrict__ td_w,
             const float* __restrict__ td_b,
             unsigned short* __restrict__ k1t, unsigned short* __restrict__ v1t)
{
    int t = blockIdx.x;      // 0..200
    int n = threadIdx.x;     // 0..127
    float a1 = 0.f, a2 = 0.f;
    if (n < DD) {
        a1 = td_b[DD + n];
        a2 = td_b[2 * DD + n];
        const float* te = temb + t * DD;
        const float* w1 = td_w + 1 * DD * DD;
        const float* w2 = td_w + 2 * DD * DD;
        for (int k = 0; k < DD; k++) {
            float x = te[k];
            a1 = fmaf(x, w1[k * DD + n], a1);
            a2 = fmaf(x, w2[k * DD + n], a2);
        }
    }
    k1t[t * KPAD + n] = f2b(a1);
    v1t[t * KPAD + n] = f2b(a2);
}

// Final pass: fp32 store straight to global, masked by valid (s_vr sign).
__device__ __forceinline__ void gemm_out(const unsigned short* IN,
                                         const unsigned short* __restrict__ WT,
                                         const float* __restrict__ bias,
                                         float* __restrict__ out,
                                         const int* s_vr, int pbase, int Mpts,
                                         int lm, int lq, int n0)
{
    const int n = n0 + lm;
    short8 bfr[4];
#pragma unroll
    for (int ks = 0; ks < 4; ks++)
        bfr[ks] = *(const short8*)(WT + n * KPAD + ks * 32 + lq * 8);
    float bv = (n < DD) ? bias[n] : 0.f;
#pragma unroll
    for (int mt = 0; mt < 4; mt++) {
        floatx4 acc = {0.f, 0.f, 0.f, 0.f};
#pragma unroll
        for (int ks = 0; ks < 4; ks++) {
            short8 a = *(const short8*)(IN + (mt * 16 + lm) * KP + ks * 32 + lq * 8);
            acc = __builtin_amdgcn_mfma_f32_16x16x32_bf16(a, bfr[ks], acc, 0, 0, 0);
        }
        if (n < DD) {
#pragma unroll
            for (int r = 0; r < 4; r++) {
                int row = mt * 16 + lq * 4 + r;
                int gp = pbase + row;
                if (gp < Mpts)
                    out[(size_t)gp * DD + n] = (s_vr[row] >= 0) ? (acc[r] + bv) : 0.f;
            }
        }
    }
}

__global__ __launch_bounds__(NTHR, 8)
void voxel_mfma_kernel(const float* __restrict__ pts,
                       const int* __restrict__ times,
                       const int* __restrict__ vox_buf,
                       const float* __restrict__ stat_f,
                       const float* __restrict__ dyn_f,
                       const float* __restrict__ td_b,
                       const float* __restrict__ sd_b,
                       const unsigned short* __restrict__ wt,
                       const unsigned short* __restrict__ k1t,
                       const unsigned short* __restrict__ v1t,
                       const float* __restrict__ fb,
                       float* __restrict__ out,
                       int Mpts)
{
    // 2 buffers only (35,328 B total => 4 blocks/CU at 8 KiB LDS granularity):
    // sA: df -> o1 -> o2 (in-place writes after per-row-block barrier)
    // sO: sf (whole kernel)
    __shared__ __align__(16) unsigned short sA[MT * KP];
    __shared__ __align__(16) unsigned short sO[MT * KP];
    __shared__ __align__(16) int s_vr[MT];   // raw voxel index; <0 => invalid
    __shared__ __align__(16) int s_ti[MT];

    const int tid  = threadIdx.x;
    const int lane = tid & 63;
    const int lm   = lane & 15;
    const int lq   = lane >> 4;
    const int wv   = tid >> 6;          // wave id = head id
    const int nn   = wv * 15 + lm;      // lane's col in head-aligned passes (<=120)
    const int n0t  = wv * 16;           // 16-col tile for the OUT gemm
    const int pbase = blockIdx.x * MT;
    const float kscale = 0.37250226f;   // log2(e)/sqrt(15)
    const float msk = (lm < 15) ? 1.f : 0.f;

    // ---- P0: fused prologue — meta chain + BOTH gathers (df->sA, sf->sO) ---
    {
        const int p   = tid >> 3;       // local point 0..63
        const int sub = tid & 7;
        const int gp  = pbase + p;
        int vr = -1, ti = 0;
        if (gp < Mpts) {
            float x = pts[3 * gp + 0];
            float y = pts[3 * gp + 1];
            float z = pts[3 * gp + 2];
            long long gx = (long long)floorf(x / 0.1f);
            long long gy = (long long)floorf(y / 0.1f);
            long long gz = (long long)floorf(z / 0.1f);
            long long hh = (gx * 73856093LL + gy * 19349669LL + gz * 83492791LL) & HASH_MASK;
            vr = vox_buf[(int)hh];
            ti = times[gp] % MODT;
        }
        if (sub == 0) { s_vr[p] = vr; s_ti[p] = ti; }
        const int vi = (vr >= 0) ? vr : 0;      // safe row even when invalid/OOB
        const float* drow = dyn_f  + (size_t)vi * DD;
        const float* srow = stat_f + (size_t)vi * DD;
#pragma unroll
        for (int j = 0; j < 4; j++) {
            int f = sub + 8 * j;                // consecutive subs -> coalesced
            if (f < 30) {
                *(uint2*)(sA + p * KP + f * 4) = pack4(*(const float4*)(drow + f * 4));
                *(uint2*)(sO + p * KP + f * 4) = pack4(*(const float4*)(srow + f * 4));
            }
        }
        if (sub == 7) {                         // zero K-pads (cols 120..127)
            *(uint4*)(sA + p * KP + 120) = make_uint4(0u, 0u, 0u, 0u);
            *(uint4*)(sO + p * KP + 120) = make_uint4(0u, 0u, 0u, 0u);
        }
    }
    __syncthreads();

    // ---- F1: fusion 1, o1 written back into sA per row-block ---------------
    // Per mt: all waves read rows [16mt,16mt+16) (and never again this phase),
    // barrier, then write o1 for those rows. Disjoint rows across iterations.
    {
        const unsigned short* w0 = wt + 0 * 16384;
        const unsigned short* w1 = wt + 1 * 16384;
        const unsigned short* w2 = wt + 2 * 16384;
        short8 bq[4], bk[4], bvv[4];
#pragma unroll
        for (int ks = 0; ks < 4; ks++) {
            bq[ks]  = *(const short8*)(w0 + nn * KPAD + ks * 32 + lq * 8);
            bk[ks]  = *(const short8*)(w1 + nn * KPAD + ks * 32 + lq * 8);
            bvv[ks] = *(const short8*)(w2 + nn * KPAD + ks * 32 + lq * 8);
        }
        const float f1bq = td_b[nn];
        const float f1bk = td_b[120 + nn];
        const float f1bv = td_b[240 + nn];
#pragma unroll
        for (int mt = 0; mt < 4; mt++) {
            short8 a[4];
#pragma unroll
            for (int ks = 0; ks < 4; ks++)
                a[ks] = *(const short8*)(sA + (mt * 16 + lm) * KP + ks * 32 + lq * 8);
            int4 tiv = *(const int4*)(&s_ti[mt * 16 + lq * 4]);
            int tt[4] = {tiv.x, tiv.y, tiv.z, tiv.w};
            float k1v[4], v1v[4];
#pragma unroll
            for (int r = 0; r < 4; r++) {
                k1v[r] = b2f(k1t[tt[r] * KPAD + nn]);   // bias folded in
                v1v[r] = b2f(v1t[tt[r] * KPAD + nn]);
            }
            floatx4 q = {0.f,0.f,0.f,0.f}, k0 = {0.f,0.f,0.f,0.f}, v0 = {0.f,0.f,0.f,0.f};
#pragma unroll
            for (int ks = 0; ks < 4; ks++) {
                q  = __builtin_amdgcn_mfma_f32_16x16x32_bf16(a[ks], bq[ks],  q,  0, 0, 0);
                k0 = __builtin_amdgcn_mfma_f32_16x16x32_bf16(a[ks], bk[ks],  k0, 0, 0, 0);
                v0 = __builtin_amdgcn_mfma_f32_16x16x32_bf16(a[ks], bvv[ks], v0, 0, 0, 0);
            }
            float o4[4];
#pragma unroll
            for (int r = 0; r < 4; r++) {
                float qf = (q[r] + f1bq) * msk;               // mask col 15h+15
                float c0 = rsum16(qf * (k0[r] + f1bk));
                float c1 = rsum16(qf * k1v[r]);
                float e  = exp2f((c1 - c0) * kscale);
                float p0 = __builtin_amdgcn_rcpf(1.f + e);    // softmax token0
                o4[r] = p0 * (v0[r] + f1bv) + (e * p0) * v1v[r];
            }
            __syncthreads();          // all reads of row-block mt complete
            if (lm < 15) {
#pragma unroll
                for (int r = 0; r < 4; r++)
                    sA[(mt * 16 + lq * 4 + r) * KP + nn] = f2b(o4[r]);
            }
        }
    }

    // ---- F2: fusion 2 with fused weights; o2 written back into sA ----------
    // q2,k20,v20 from sf (sO); k21 = o1@W31, v21 = o1@W32 from sA. No cond.
    {
        const unsigned short* u0  = wt + 4 * 16384;
        const unsigned short* u1  = wt + 5 * 16384;
        const unsigned short* u2  = wt + 6 * 16384;
        const unsigned short* w31 = wt + 8 * 16384;
        const unsigned short* w32 = wt + 9 * 16384;
        const float f2bq = sd_b[nn];
        const float f2bk = sd_b[120 + nn];
        const float f2bv = sd_b[240 + nn];
        const float fbk1 = fb[nn];          // b3@U1 + b_k2 (0 in pads)
        const float fbv1 = fb[128 + nn];    // b3@U2 + b_v2
#pragma unroll
        for (int mt = 0; mt < 4; mt++) {
            short8 a[4], s[4];
#pragma unroll
            for (int ks = 0; ks < 4; ks++) {
                a[ks] = *(const short8*)(sA + (mt * 16 + lm) * KP + ks * 32 + lq * 8);
                s[ks] = *(const short8*)(sO + (mt * 16 + lm) * KP + ks * 32 + lq * 8);
            }
            floatx4 q = {0.f,0.f,0.f,0.f}, k20 = {0.f,0.f,0.f,0.f}, k21 = {0.f,0.f,0.f,0.f};
#pragma unroll
            for (int ks = 0; ks < 4; ks++) {
                short8 b0 = *(const short8*)(u0  + nn * KPAD + ks * 32 + lq * 8);
                short8 b1 = *(const short8*)(u1  + nn * KPAD + ks * 32 + lq * 8);
                short8 bw = *(const short8*)(w31 + nn * KPAD + ks * 32 + lq * 8);
                q   = __builtin_amdgcn_mfma_f32_16x16x32_bf16(s[ks], b0, q,   0, 0, 0);
                k20 = __builtin_amdgcn_mfma_f32_16x16x32_bf16(s[ks], b1, k20, 0, 0, 0);
                k21 = __builtin_amdgcn_mfma_f32_16x16x32_bf16(a[ks], bw, k21, 0, 0, 0);
            }
            float p0a[4], p1a[4];
#pragma unroll
            for (int r = 0; r < 4; r++) {
                float qf = (q[r] + f2bq) * msk;
                float c0 = rsum16(qf * (k20[r] + f2bk));
                float c1 = rsum16(qf * (k21[r] + fbk1));
                float e  = exp2f((c1 - c0) * kscale);
                p0a[r] = __builtin_amdgcn_rcpf(1.f + e);
                p1a[r] = e * p0a[r];
            }
            floatx4 v20 = {0.f,0.f,0.f,0.f}, v21 = {0.f,0.f,0.f,0.f};
#pragma unroll
            for (int ks = 0; ks < 4; ks++) {
                short8 b2  = *(const short8*)(u2  + nn * KPAD + ks * 32 + lq * 8);
                short8 bw2 = *(const short8*)(w32 + nn * KPAD + ks * 32 + lq * 8);
                v20 = __builtin_amdgcn_mfma_f32_16x16x32_bf16(s[ks], b2,  v20, 0, 0, 0);
                v21 = __builtin_amdgcn_mfma_f32_16x16x32_bf16(a[ks], bw2, v21, 0, 0, 0);
            }
            float o4[4];
#pragma unroll
            for (int r = 0; r < 4; r++)
                o4[r] = p0a[r] * (v20[r] + f2bv) + p1a[r] * (v21[r] + fbv1);
            __syncthreads();          // all reads of row-block mt complete
            if (lm < 15) {
#pragma unroll
                for (int r = 0; r < 4; r++)
                    sA[(mt * 16 + lq * 4 + r) * KP + nn] = f2b(o4[r]);
            }
        }
    }
    __syncthreads();

    // ---- OUT: out = o2 @ U3 + b, masked ------------------------------------
    gemm_out(sA, wt + 7 * 16384, sd_b + 360, out, s_vr, pbase, Mpts, lm, lq, n0t);
}

extern "C" void kernel_launch(void* const* d_in, const int* in_sizes, int n_in,
                              void* d_out, int out_size, void* d_ws, size_t ws_size,
                              hipStream_t stream) {
    const float* pts   = (const float*)d_in[0];
    const int*   times = (const int*)d_in[1];
    const int*   vox   = (const int*)d_in[2];
    const float* statf = (const float*)d_in[3];
    const float* dynf  = (const float*)d_in[4];
    const float* temb  = (const float*)d_in[5];
    const float* td_w  = (const float*)d_in[6];
    const float* td_b  = (const float*)d_in[7];
    const float* sd_w  = (const float*)d_in[8];
    const float* sd_b  = (const float*)d_in[9];

    unsigned short* wt  = (unsigned short*)d_ws;   // 10 mats * 128*128 bf16 = 320 KB
    unsigned short* k1t = wt + 10 * 128 * 128;     // 201*128 bf16
    unsigned short* v1t = k1t + 201 * 128;         // 201*128 bf16
    float*          fb  = (float*)(v1t + 201 * 128); // 2*128 fp32 fused biases

    prep_weights<<<512, 256, 0, stream>>>(td_w, sd_w, wt);
    prep_fused<<<128, 256, 0, stream>>>(td_w, td_b, sd_w, sd_b, wt + 8 * 16384, fb);
    prep_te<<<201, 128, 0, stream>>>(temb, td_w, td_b, k1t, v1t);

    int Mpts = in_sizes[0] / 3;
    int blocks = (Mpts + MT - 1) / MT;
    voxel_mfma_kernel<<<blocks, NTHR, 0, stream>>>(
        pts, times, vox, statf, dynf, td_b, sd_b, wt, k1t, v1t, fb,
        (float*)d_out, Mpts);
}